// Round 2
// baseline (7212.823 us; speedup 1.0000x reference)
//
#include <hip/hip_runtime.h>
#include <hip/hip_bf16.h>
#include <cstdint>
#include <cstddef>

#define B_ 64
#define T_ 512
#define E_ 512
#define H_ 1024
#define V_ 32000
#define BK 64

typedef __attribute__((ext_vector_type(8))) short bf16x8;
typedef __attribute__((ext_vector_type(4))) float f32x4;
typedef __attribute__((ext_vector_type(4))) float float4_t;

static __device__ __forceinline__ unsigned short f2b(float f) {
  union { float f; unsigned int u; } v; v.f = f;
  unsigned int u = v.u;
  unsigned int r = (u + 0x7FFFu + ((u >> 16) & 1u)) >> 16;  // RNE
  return (unsigned short)r;
}
static __device__ __forceinline__ float b2f(unsigned short s) {
  union { unsigned int u; float f; } v; v.u = ((unsigned int)s) << 16;
  return v.f;
}
static __device__ __forceinline__ bf16x8 cvt8(const float* p) {
  bf16x8 r;
#pragma unroll
  for (int i = 0; i < 8; i++) r[i] = (short)f2b(p[i]);
  return r;
}
// LDS swizzle for 128-byte rows (BK=64 bf16): spread 16 rows across banks
static __device__ __forceinline__ int swz128(int row, int byte_off) {
  return row * 128 + (byte_off ^ ((row & 7) << 4));
}

#define NFLAGS 4096  // 256 flags x 16 uints (64B spacing)

// ---------------- init: zero h0 and flag array ----------------
__global__ void k_init(unsigned short* hb0, unsigned int* flags) {
  int i = blockIdx.x * blockDim.x + threadIdx.x;
  if (i < B_ * H_) hb0[i] = 0;  // bf16 zero
  if (i < NFLAGS) flags[i] = 0u;
}

// ---------------- E2 = emb @ W_ih^T  [V,H] bf16 ----------------
// grid (16, 500), 256 threads, 64x64 tile, BK=64
__global__ __launch_bounds__(256)
void k_e2(const float* __restrict__ emb, const float* __restrict__ Wih,
          unsigned short* __restrict__ E2) {
  __shared__ unsigned char As[64 * 128];
  __shared__ unsigned char Bs[64 * 128];
  const int tid = threadIdx.x;
  const int lane = tid & 63;
  const int w = tid >> 6;                 // wave id = M sub-tile
  const int n0 = blockIdx.x * 64;         // over H
  const int m0 = blockIdx.y * 64;         // over V
  f32x4 acc[4];
#pragma unroll
  for (int i = 0; i < 4; i++) acc[i] = (f32x4)0.0f;

  for (int kc = 0; kc < E_ / BK; kc++) {
    const int k0 = kc * BK;
    __syncthreads();
#pragma unroll
    for (int it = 0; it < 2; it++) {
      int idx = tid + it * 256;           // 512 chunks of 8
      int r = idx >> 3;                   // 0..63
      int k = (idx & 7) * 8;              // 0..56
      float tmp[8];
      *(float4_t*)(tmp)     = *(const float4_t*)(emb + (size_t)(m0 + r) * E_ + k0 + k);
      *(float4_t*)(tmp + 4) = *(const float4_t*)(emb + (size_t)(m0 + r) * E_ + k0 + k + 4);
      *(bf16x8*)(As + swz128(r, k * 2)) = cvt8(tmp);
      *(float4_t*)(tmp)     = *(const float4_t*)(Wih + (size_t)(n0 + r) * E_ + k0 + k);
      *(float4_t*)(tmp + 4) = *(const float4_t*)(Wih + (size_t)(n0 + r) * E_ + k0 + k + 4);
      *(bf16x8*)(Bs + swz128(r, k * 2)) = cvt8(tmp);
    }
    __syncthreads();
#pragma unroll
    for (int kk = 0; kk < 2; kk++) {
      int kb = kk * 64 + (lane >> 4) * 16;
      bf16x8 a = *(const bf16x8*)(As + swz128(w * 16 + (lane & 15), kb));
#pragma unroll
      for (int nt = 0; nt < 4; nt++) {
        bf16x8 b = *(const bf16x8*)(Bs + swz128(nt * 16 + (lane & 15), kb));
        acc[nt] = __builtin_amdgcn_mfma_f32_16x16x32_bf16(a, b, acc[nt], 0, 0, 0);
      }
    }
  }
#pragma unroll
  for (int nt = 0; nt < 4; nt++) {
#pragma unroll
    for (int reg = 0; reg < 4; reg++) {
      int row = m0 + w * 16 + (lane >> 4) * 4 + reg;
      int col = n0 + nt * 16 + (lane & 15);
      E2[(size_t)row * H_ + col] = f2b(acc[nt][reg]);
    }
  }
}

// ---------------- persistent scan over T ----------------
// 64 blocks x 4 waves. Block n owns cols [n*16, n*16+16); wave w owns batch
// rows [w*16, w*16+16). Four independent barrier domains (one per wave index,
// since batch rows are independent). Flag array: flags[(w*64 + block)*16],
// each flag on its own 64B line -> parallel release stores, no RMW
// serialization. Poll = 1 lane-parallel relaxed load + __all, acquire fence
// on exit only.
__global__ __launch_bounds__(256, 1)
void k_scan(const int* __restrict__ hist, const float* __restrict__ Whh,
            const unsigned short* __restrict__ E2,
            unsigned short* __restrict__ hb0, unsigned short* __restrict__ hb1,
            unsigned int* __restrict__ flags, float* __restrict__ out_h) {
  const int tid = threadIdx.x;
  const int lane = tid & 63;
  const int w = tid >> 6;                 // wave index = batch-row group
  const int bid = blockIdx.x;
  const int n0 = bid * 16;                // col base

  // Preload B-fragments: lane holds W_hh[n0+(lane&15)][kk*32+(lane>>4)*8 + j]
  bf16x8 Breg[32];
  {
    const float* wrow = Whh + (size_t)(n0 + (lane & 15)) * H_ + (lane >> 4) * 8;
#pragma unroll
    for (int kk = 0; kk < 32; kk++) {
      float tmp[8];
      *(float4_t*)(tmp)     = *(const float4_t*)(wrow + kk * 32);
      *(float4_t*)(tmp + 4) = *(const float4_t*)(wrow + kk * 32 + 4);
      Breg[kk] = cvt8(tmp);
    }
  }

  const int rowb = w * 16 + ((lane >> 4) << 2);   // C-row base for this lane
  const int colc = lane & 15;                     // C-col (local)
  unsigned int* myflag   = flags + (size_t)(w * 64 + bid) * 16;
  unsigned int* pollflag = flags + (size_t)(w * 64 + lane) * 16;

  for (int t = 0; t < T_; t++) {
    const unsigned short* hc = (t & 1) ? hb1 : hb0;
    unsigned short*       hn = (t & 1) ? hb0 : hb1;

    // xi gather into registers (independent of flags -> hides under poll)
    float xiv[4];
    {
      int tok[4];
#pragma unroll
      for (int r = 0; r < 4; r++) tok[r] = hist[(size_t)(rowb + r) * T_ + t];
#pragma unroll
      for (int r = 0; r < 4; r++)
        xiv[r] = b2f(E2[(size_t)tok[r] * H_ + n0 + colc]);
    }

    // wait for all 64 blocks' wave-w slices of h_{t-1}
    if (t > 0) {
      const unsigned int e = (unsigned int)t;
      for (;;) {
        unsigned int f = __hip_atomic_load(pollflag, __ATOMIC_RELAXED,
                                           __HIP_MEMORY_SCOPE_AGENT);
        if (__all(f >= e)) break;
        __builtin_amdgcn_s_sleep(1);
      }
      __builtin_amdgcn_fence(__ATOMIC_ACQUIRE, "agent");
    }

    // C[16x16] = h_rows(w) @ Wslice^T, two interleaved acc chains
    f32x4 acc0 = (f32x4)0.0f, acc1 = (f32x4)0.0f;
    const unsigned short* arow =
        hc + (size_t)(w * 16 + (lane & 15)) * H_ + (lane >> 4) * 8;
#pragma unroll
    for (int kk = 0; kk < 32; kk += 2) {
      bf16x8 a0 = *(const bf16x8*)(arow + kk * 32);
      bf16x8 a1 = *(const bf16x8*)(arow + kk * 32 + 32);
      acc0 = __builtin_amdgcn_mfma_f32_16x16x32_bf16(a0, Breg[kk],     acc0, 0, 0, 0);
      acc1 = __builtin_amdgcn_mfma_f32_16x16x32_bf16(a1, Breg[kk + 1], acc1, 0, 0, 0);
    }

#pragma unroll
    for (int reg = 0; reg < 4; reg++) {
      int row = rowb + reg;                       // batch index
      float pre = acc0[reg] + acc1[reg] + xiv[reg];
      float hval = tanhf(pre);
      hn[(size_t)row * H_ + n0 + colc] = f2b(hval);
      if (t == T_ - 1) out_h[(size_t)row * H_ + n0 + colc] = hval;  // fp32
    }

    // signal: release store to own cache line (orders prior h stores)
    if (lane == 0)
      __hip_atomic_store(myflag, (unsigned int)(t + 1), __ATOMIC_RELEASE,
                         __HIP_MEMORY_SCOPE_AGENT);
  }
}

// ---------------- logits = h_final @ W_cls^T + b ----------------
// grid 500 blocks (64 vocab cols each), 256 threads
__global__ __launch_bounds__(256)
void k_logits(const unsigned short* __restrict__ hb,
              const float* __restrict__ Wcls, const float* __restrict__ bcls,
              float* __restrict__ out) {
  __shared__ unsigned char Bs[64 * 128];
  const int tid = threadIdx.x;
  const int lane = tid & 63;
  const int w = tid >> 6;
  const int n0 = blockIdx.x * 64;
  f32x4 acc[4];
#pragma unroll
  for (int i = 0; i < 4; i++) acc[i] = (f32x4)0.0f;

  for (int kc = 0; kc < H_ / BK; kc++) {
    const int k0 = kc * BK;
    __syncthreads();
#pragma unroll
    for (int it = 0; it < 2; it++) {
      int idx = tid + it * 256;
      int r = idx >> 3;
      int k = (idx & 7) * 8;
      float tmp[8];
      *(float4_t*)(tmp)     = *(const float4_t*)(Wcls + (size_t)(n0 + r) * H_ + k0 + k);
      *(float4_t*)(tmp + 4) = *(const float4_t*)(Wcls + (size_t)(n0 + r) * H_ + k0 + k + 4);
      *(bf16x8*)(Bs + swz128(r, k * 2)) = cvt8(tmp);
    }
    __syncthreads();
#pragma unroll
    for (int kk = 0; kk < 2; kk++) {
      const unsigned short* ap =
          hb + (size_t)(w * 16 + (lane & 15)) * H_ + k0 + kk * 32 + (lane >> 4) * 8;
      bf16x8 a = *(const bf16x8*)ap;
      int kb = kk * 64 + (lane >> 4) * 16;
#pragma unroll
      for (int nt = 0; nt < 4; nt++) {
        bf16x8 b = *(const bf16x8*)(Bs + swz128(nt * 16 + (lane & 15), kb));
        acc[nt] = __builtin_amdgcn_mfma_f32_16x16x32_bf16(a, b, acc[nt], 0, 0, 0);
      }
    }
  }
#pragma unroll
  for (int nt = 0; nt < 4; nt++) {
    int col = n0 + nt * 16 + (lane & 15);
    float bias = bcls[col];
#pragma unroll
    for (int reg = 0; reg < 4; reg++) {
      int row = w * 16 + (lane >> 4) * 4 + reg;
      out[(size_t)row * V_ + col] = acc[nt][reg] + bias;
    }
  }
}

extern "C" void kernel_launch(void* const* d_in, const int* in_sizes, int n_in,
                              void* d_out, int out_size, void* d_ws, size_t ws_size,
                              hipStream_t stream) {
  const int*   hist = (const int*)d_in[0];
  const float* emb  = (const float*)d_in[1];
  const float* Wih  = (const float*)d_in[2];
  const float* Whh  = (const float*)d_in[3];
  const float* Wcls = (const float*)d_in[4];
  const float* bcls = (const float*)d_in[5];
  float* out = (float*)d_out;

  unsigned char* ws = (unsigned char*)d_ws;
  const size_t E2_BYTES = (size_t)V_ * H_ * 2;        // 65,536,000
  const size_t HB_BYTES = (size_t)B_ * H_ * 2;        // 131,072
  unsigned short* E2    = (unsigned short*)ws;
  unsigned short* hb0   = (unsigned short*)(ws + E2_BYTES);
  unsigned short* hb1   = (unsigned short*)(ws + E2_BYTES + HB_BYTES);
  unsigned int*   flags = (unsigned int*)(ws + E2_BYTES + 2 * HB_BYTES);

  k_init<<<256, 256, 0, stream>>>(hb0, flags);
  k_e2<<<dim3(16, 500), 256, 0, stream>>>(emb, Wih, E2);
  k_scan<<<64, 256, 0, stream>>>(hist, Whh, E2, hb0, hb1, flags,
                                 out + (size_t)B_ * V_);
  k_logits<<<500, 256, 0, stream>>>(hb0, Wcls, bcls, out);
}

// Round 3
// 6654.296 us; speedup vs baseline: 1.0839x; 1.0839x over previous
//
#include <hip/hip_runtime.h>
#include <hip/hip_bf16.h>
#include <cstdint>
#include <cstddef>

#define B_ 64
#define T_ 512
#define E_ 512
#define H_ 1024
#define V_ 32000
#define BK 64

typedef __attribute__((ext_vector_type(8))) short bf16x8;
typedef __attribute__((ext_vector_type(4))) float f32x4;
typedef __attribute__((ext_vector_type(4))) float float4_t;

static __device__ __forceinline__ unsigned short f2b(float f) {
  union { float f; unsigned int u; } v; v.f = f;
  unsigned int u = v.u;
  unsigned int r = (u + 0x7FFFu + ((u >> 16) & 1u)) >> 16;  // RNE
  return (unsigned short)r;
}
static __device__ __forceinline__ float b2f(unsigned short s) {
  union { unsigned int u; float f; } v; v.u = ((unsigned int)s) << 16;
  return v.f;
}
static __device__ __forceinline__ bf16x8 cvt8(const float* p) {
  bf16x8 r;
#pragma unroll
  for (int i = 0; i < 8; i++) r[i] = (short)f2b(p[i]);
  return r;
}
// LDS swizzle for 128-byte rows (BK=64 bf16): spread 16 rows across banks
static __device__ __forceinline__ int swz128(int row, int byte_off) {
  return row * 128 + (byte_off ^ ((row & 7) << 4));
}

#define NFLAGS 4224  // 256 arrive-flag lines + 4 go lines (16 uints = 64B each)

// ---------------- init: zero h0 and flag array ----------------
__global__ void k_init(unsigned short* hb0, unsigned int* flags) {
  int i = blockIdx.x * blockDim.x + threadIdx.x;
  if (i < B_ * H_) hb0[i] = 0;  // bf16 zero
  if (i < NFLAGS) flags[i] = 0u;
}

// ---------------- E2 = emb @ W_ih^T  [V,H] bf16 ----------------
// grid (16, 500), 256 threads, 64x64 tile, BK=64
__global__ __launch_bounds__(256)
void k_e2(const float* __restrict__ emb, const float* __restrict__ Wih,
          unsigned short* __restrict__ E2) {
  __shared__ unsigned char As[64 * 128];
  __shared__ unsigned char Bs[64 * 128];
  const int tid = threadIdx.x;
  const int lane = tid & 63;
  const int w = tid >> 6;                 // wave id = M sub-tile
  const int n0 = blockIdx.x * 64;         // over H
  const int m0 = blockIdx.y * 64;         // over V
  f32x4 acc[4];
#pragma unroll
  for (int i = 0; i < 4; i++) acc[i] = (f32x4)0.0f;

  for (int kc = 0; kc < E_ / BK; kc++) {
    const int k0 = kc * BK;
    __syncthreads();
#pragma unroll
    for (int it = 0; it < 2; it++) {
      int idx = tid + it * 256;           // 512 chunks of 8
      int r = idx >> 3;                   // 0..63
      int k = (idx & 7) * 8;              // 0..56
      float tmp[8];
      *(float4_t*)(tmp)     = *(const float4_t*)(emb + (size_t)(m0 + r) * E_ + k0 + k);
      *(float4_t*)(tmp + 4) = *(const float4_t*)(emb + (size_t)(m0 + r) * E_ + k0 + k + 4);
      *(bf16x8*)(As + swz128(r, k * 2)) = cvt8(tmp);
      *(float4_t*)(tmp)     = *(const float4_t*)(Wih + (size_t)(n0 + r) * E_ + k0 + k);
      *(float4_t*)(tmp + 4) = *(const float4_t*)(Wih + (size_t)(n0 + r) * E_ + k0 + k + 4);
      *(bf16x8*)(Bs + swz128(r, k * 2)) = cvt8(tmp);
    }
    __syncthreads();
#pragma unroll
    for (int kk = 0; kk < 2; kk++) {
      int kb = kk * 64 + (lane >> 4) * 16;
      bf16x8 a = *(const bf16x8*)(As + swz128(w * 16 + (lane & 15), kb));
#pragma unroll
      for (int nt = 0; nt < 4; nt++) {
        bf16x8 b = *(const bf16x8*)(Bs + swz128(nt * 16 + (lane & 15), kb));
        acc[nt] = __builtin_amdgcn_mfma_f32_16x16x32_bf16(a, b, acc[nt], 0, 0, 0);
      }
    }
  }
#pragma unroll
  for (int nt = 0; nt < 4; nt++) {
#pragma unroll
    for (int reg = 0; reg < 4; reg++) {
      int row = m0 + w * 16 + (lane >> 4) * 4 + reg;
      int col = n0 + nt * 16 + (lane & 15);
      E2[(size_t)row * H_ + col] = f2b(acc[nt][reg]);
    }
  }
}

// ---------------- persistent scan over T ----------------
// 65 blocks x 4 waves. Compute blocks 0..63: block n owns cols [n*16,n*16+16),
// wave w owns batch rows [w*16, w*16+16) (4 independent sync domains).
// Block 64 = dedicated aggregator: wave w polls domain w's 64 arrive lines
// (one wave-wide load/iter), wave-min via shfl_xor, release-stores go[w].
// Consumers poll the single go[w] word (uniform address, 1 line/poll).
// Release chain: producer REL(arrive) -> aggregator ACQ + REL(go) ->
// consumer ACQ -> h reads. Transitive happens-before, no RMWs anywhere.
__global__ __launch_bounds__(256, 1)
void k_scan(const int* __restrict__ hist, const float* __restrict__ Whh,
            const unsigned short* __restrict__ E2,
            unsigned short* __restrict__ hb0, unsigned short* __restrict__ hb1,
            unsigned int* __restrict__ flags, float* __restrict__ out_h) {
  const int tid = threadIdx.x;
  const int lane = tid & 63;
  const int w = tid >> 6;                 // wave index = batch-row group
  const int bid = blockIdx.x;

  unsigned int* arrive = flags;           // 256 lines
  unsigned int* go     = flags + 256 * 16;  // 4 lines

  if (bid == 64) {
    // ---- aggregator ----
    unsigned int* af = arrive + (size_t)(w * 64 + lane) * 16;
    unsigned int* gw = go + (size_t)w * 16;
    unsigned int last = 0;
    while (last < (unsigned int)T_) {
      unsigned int f = __hip_atomic_load(af, __ATOMIC_RELAXED,
                                         __HIP_MEMORY_SCOPE_AGENT);
      unsigned int m = f;
#pragma unroll
      for (int s = 32; s; s >>= 1) {
        unsigned int o = (unsigned int)__shfl_xor((int)m, s, 64);
        m = m < o ? m : o;
      }
      if (m > last) {
        __builtin_amdgcn_fence(__ATOMIC_ACQUIRE, "agent");
        if (lane == 0)
          __hip_atomic_store(gw, m, __ATOMIC_RELEASE, __HIP_MEMORY_SCOPE_AGENT);
        last = m;
      } else {
        __builtin_amdgcn_s_sleep(1);
      }
    }
    return;
  }

  const int n0 = bid * 16;                // col base

  // Preload B-fragments: lane holds W_hh[n0+(lane&15)][kk*32+(lane>>4)*8 + j]
  bf16x8 Breg[32];
  {
    const float* wrow = Whh + (size_t)(n0 + (lane & 15)) * H_ + (lane >> 4) * 8;
#pragma unroll
    for (int kk = 0; kk < 32; kk++) {
      float tmp[8];
      *(float4_t*)(tmp)     = *(const float4_t*)(wrow + kk * 32);
      *(float4_t*)(tmp + 4) = *(const float4_t*)(wrow + kk * 32 + 4);
      Breg[kk] = cvt8(tmp);
    }
  }

  const int rowb = w * 16 + ((lane >> 4) << 2);   // C-row base for this lane
  const int colc = lane & 15;                     // C-col (local)
  unsigned int* myflag = arrive + (size_t)(w * 64 + bid) * 16;
  unsigned int* gw     = go + (size_t)w * 16;

  for (int t = 0; t < T_; t++) {
    const unsigned short* hc = (t & 1) ? hb1 : hb0;
    unsigned short*       hn = (t & 1) ? hb0 : hb1;

    // xi gather into registers (independent of flags -> hides under poll)
    float xiv[4];
    {
      int tok[4];
#pragma unroll
      for (int r = 0; r < 4; r++) tok[r] = hist[(size_t)(rowb + r) * T_ + t];
#pragma unroll
      for (int r = 0; r < 4; r++)
        xiv[r] = b2f(E2[(size_t)tok[r] * H_ + n0 + colc]);
    }

    // wait for domain-w h_{t-1}: poll single go word
    if (t > 0) {
      const unsigned int e = (unsigned int)t;
      while (__hip_atomic_load(gw, __ATOMIC_RELAXED,
                               __HIP_MEMORY_SCOPE_AGENT) < e)
        __builtin_amdgcn_s_sleep(2);
      __builtin_amdgcn_fence(__ATOMIC_ACQUIRE, "agent");
    }

    // C[16x16] = h_rows(w) @ Wslice^T, two interleaved acc chains
    f32x4 acc0 = (f32x4)0.0f, acc1 = (f32x4)0.0f;
    const unsigned short* arow =
        hc + (size_t)(w * 16 + (lane & 15)) * H_ + (lane >> 4) * 8;
#pragma unroll
    for (int kk = 0; kk < 32; kk += 2) {
      bf16x8 a0 = *(const bf16x8*)(arow + kk * 32);
      bf16x8 a1 = *(const bf16x8*)(arow + kk * 32 + 32);
      acc0 = __builtin_amdgcn_mfma_f32_16x16x32_bf16(a0, Breg[kk],     acc0, 0, 0, 0);
      acc1 = __builtin_amdgcn_mfma_f32_16x16x32_bf16(a1, Breg[kk + 1], acc1, 0, 0, 0);
    }

#pragma unroll
    for (int reg = 0; reg < 4; reg++) {
      int row = rowb + reg;                       // batch index
      float pre = acc0[reg] + acc1[reg] + xiv[reg];
      float hval = tanhf(pre);
      hn[(size_t)row * H_ + n0 + colc] = f2b(hval);
      if (t == T_ - 1) out_h[(size_t)row * H_ + n0 + colc] = hval;  // fp32
    }

    // signal: release store to own cache line (orders prior h stores;
    // vmcnt drain is wave-wide so the whole wave's slice is covered)
    if (lane == 0)
      __hip_atomic_store(myflag, (unsigned int)(t + 1), __ATOMIC_RELEASE,
                         __HIP_MEMORY_SCOPE_AGENT);
  }
}

// ---------------- logits = h_final @ W_cls^T + b ----------------
// grid 500 blocks (64 vocab cols each), 256 threads
__global__ __launch_bounds__(256)
void k_logits(const unsigned short* __restrict__ hb,
              const float* __restrict__ Wcls, const float* __restrict__ bcls,
              float* __restrict__ out) {
  __shared__ unsigned char Bs[64 * 128];
  const int tid = threadIdx.x;
  const int lane = tid & 63;
  const int w = tid >> 6;
  const int n0 = blockIdx.x * 64;
  f32x4 acc[4];
#pragma unroll
  for (int i = 0; i < 4; i++) acc[i] = (f32x4)0.0f;

  for (int kc = 0; kc < H_ / BK; kc++) {
    const int k0 = kc * BK;
    __syncthreads();
#pragma unroll
    for (int it = 0; it < 2; it++) {
      int idx = tid + it * 256;
      int r = idx >> 3;
      int k = (idx & 7) * 8;
      float tmp[8];
      *(float4_t*)(tmp)     = *(const float4_t*)(Wcls + (size_t)(n0 + r) * H_ + k0 + k);
      *(float4_t*)(tmp + 4) = *(const float4_t*)(Wcls + (size_t)(n0 + r) * H_ + k0 + k + 4);
      *(bf16x8*)(Bs + swz128(r, k * 2)) = cvt8(tmp);
    }
    __syncthreads();
#pragma unroll
    for (int kk = 0; kk < 2; kk++) {
      const unsigned short* ap =
          hb + (size_t)(w * 16 + (lane & 15)) * H_ + k0 + kk * 32 + (lane >> 4) * 8;
      bf16x8 a = *(const bf16x8*)ap;
      int kb = kk * 64 + (lane >> 4) * 16;
#pragma unroll
      for (int nt = 0; nt < 4; nt++) {
        bf16x8 b = *(const bf16x8*)(Bs + swz128(nt * 16 + (lane & 15), kb));
        acc[nt] = __builtin_amdgcn_mfma_f32_16x16x32_bf16(a, b, acc[nt], 0, 0, 0);
      }
    }
  }
#pragma unroll
  for (int nt = 0; nt < 4; nt++) {
    int col = n0 + nt * 16 + (lane & 15);
    float bias = bcls[col];
#pragma unroll
    for (int reg = 0; reg < 4; reg++) {
      int row = w * 16 + (lane >> 4) * 4 + reg;
      out[(size_t)row * V_ + col] = acc[nt][reg] + bias;
    }
  }
}

extern "C" void kernel_launch(void* const* d_in, const int* in_sizes, int n_in,
                              void* d_out, int out_size, void* d_ws, size_t ws_size,
                              hipStream_t stream) {
  const int*   hist = (const int*)d_in[0];
  const float* emb  = (const float*)d_in[1];
  const float* Wih  = (const float*)d_in[2];
  const float* Whh  = (const float*)d_in[3];
  const float* Wcls = (const float*)d_in[4];
  const float* bcls = (const float*)d_in[5];
  float* out = (float*)d_out;

  unsigned char* ws = (unsigned char*)d_ws;
  const size_t E2_BYTES = (size_t)V_ * H_ * 2;        // 65,536,000
  const size_t HB_BYTES = (size_t)B_ * H_ * 2;        // 131,072
  unsigned short* E2    = (unsigned short*)ws;
  unsigned short* hb0   = (unsigned short*)(ws + E2_BYTES);
  unsigned short* hb1   = (unsigned short*)(ws + E2_BYTES + HB_BYTES);
  unsigned int*   flags = (unsigned int*)(ws + E2_BYTES + 2 * HB_BYTES);

  k_init<<<256, 256, 0, stream>>>(hb0, flags);
  k_e2<<<dim3(16, 500), 256, 0, stream>>>(emb, Wih, E2);
  k_scan<<<65, 256, 0, stream>>>(hist, Whh, E2, hb0, hb1, flags,
                                 out + (size_t)B_ * V_);
  k_logits<<<500, 256, 0, stream>>>(hb0, Wcls, bcls, out);
}

// Round 4
// 5250.811 us; speedup vs baseline: 1.3737x; 1.2673x over previous
//
#include <hip/hip_runtime.h>
#include <hip/hip_bf16.h>
#include <cstdint>
#include <cstddef>

#define B_ 64
#define T_ 512
#define E_ 512
#define H_ 1024
#define V_ 32000
#define BK 64

typedef __attribute__((ext_vector_type(8))) short bf16x8;
typedef __attribute__((ext_vector_type(4))) float f32x4;
typedef __attribute__((ext_vector_type(4))) float float4_t;
typedef unsigned long long ull;

static __device__ __forceinline__ unsigned short f2b(float f) {
  union { float f; unsigned int u; } v; v.f = f;
  unsigned int u = v.u;
  unsigned int r = (u + 0x7FFFu + ((u >> 16) & 1u)) >> 16;  // RNE
  return (unsigned short)r;
}
static __device__ __forceinline__ float b2f(unsigned short s) {
  union { unsigned int u; float f; } v; v.u = ((unsigned int)s) << 16;
  return v.f;
}
static __device__ __forceinline__ bf16x8 cvt8(const float* p) {
  bf16x8 r;
#pragma unroll
  for (int i = 0; i < 8; i++) r[i] = (short)f2b(p[i]);
  return r;
}
static __device__ __forceinline__ bf16x8 mk8(ull lo, ull hi) {
  union { ull u[2]; bf16x8 v; } c; c.u[0] = lo; c.u[1] = hi; return c.v;
}
// relaxed agent-scope (sc1) 8B load: coherent at MALL, NO cache maintenance
static __device__ __forceinline__ ull ald(const ull* p) {
  return __hip_atomic_load(p, __ATOMIC_RELAXED, __HIP_MEMORY_SCOPE_AGENT);
}
// LDS swizzle for 128-byte rows (BK=64 bf16): spread 16 rows across banks
static __device__ __forceinline__ int swz128(int row, int byte_off) {
  return row * 128 + (byte_off ^ ((row & 7) << 4));
}

#define NFLAGS 256

// ---------------- init: zero h0 and flag array ----------------
__global__ void k_init(unsigned short* hb0, unsigned int* flags) {
  int i = blockIdx.x * blockDim.x + threadIdx.x;
  if (i < B_ * H_) hb0[i] = 0;  // bf16 zero
  if (i < NFLAGS) flags[i] = 0u;
}

// ---------------- E2 = emb @ W_ih^T  [V,H] bf16 ----------------
// grid (16, 500), 256 threads, 64x64 tile, BK=64
__global__ __launch_bounds__(256)
void k_e2(const float* __restrict__ emb, const float* __restrict__ Wih,
          unsigned short* __restrict__ E2) {
  __shared__ unsigned char As[64 * 128];
  __shared__ unsigned char Bs[64 * 128];
  const int tid = threadIdx.x;
  const int lane = tid & 63;
  const int w = tid >> 6;                 // wave id = M sub-tile
  const int n0 = blockIdx.x * 64;         // over H
  const int m0 = blockIdx.y * 64;         // over V
  f32x4 acc[4];
#pragma unroll
  for (int i = 0; i < 4; i++) acc[i] = (f32x4)0.0f;

  for (int kc = 0; kc < E_ / BK; kc++) {
    const int k0 = kc * BK;
    __syncthreads();
#pragma unroll
    for (int it = 0; it < 2; it++) {
      int idx = tid + it * 256;           // 512 chunks of 8
      int r = idx >> 3;                   // 0..63
      int k = (idx & 7) * 8;              // 0..56
      float tmp[8];
      *(float4_t*)(tmp)     = *(const float4_t*)(emb + (size_t)(m0 + r) * E_ + k0 + k);
      *(float4_t*)(tmp + 4) = *(const float4_t*)(emb + (size_t)(m0 + r) * E_ + k0 + k + 4);
      *(bf16x8*)(As + swz128(r, k * 2)) = cvt8(tmp);
      *(float4_t*)(tmp)     = *(const float4_t*)(Wih + (size_t)(n0 + r) * E_ + k0 + k);
      *(float4_t*)(tmp + 4) = *(const float4_t*)(Wih + (size_t)(n0 + r) * E_ + k0 + k + 4);
      *(bf16x8*)(Bs + swz128(r, k * 2)) = cvt8(tmp);
    }
    __syncthreads();
#pragma unroll
    for (int kk = 0; kk < 2; kk++) {
      int kb = kk * 64 + (lane >> 4) * 16;
      bf16x8 a = *(const bf16x8*)(As + swz128(w * 16 + (lane & 15), kb));
#pragma unroll
      for (int nt = 0; nt < 4; nt++) {
        bf16x8 b = *(const bf16x8*)(Bs + swz128(nt * 16 + (lane & 15), kb));
        acc[nt] = __builtin_amdgcn_mfma_f32_16x16x32_bf16(a, b, acc[nt], 0, 0, 0);
      }
    }
  }
#pragma unroll
  for (int nt = 0; nt < 4; nt++) {
#pragma unroll
    for (int reg = 0; reg < 4; reg++) {
      int row = m0 + w * 16 + (lane >> 4) * 4 + reg;
      int col = n0 + nt * 16 + (lane & 15);
      E2[(size_t)row * H_ + col] = f2b(acc[nt][reg]);
    }
  }
}

// ---------------- persistent scan over T ----------------
// 64 blocks x 4 waves. Block n owns cols [n*16, n*16+16) for ALL 64 batch
// rows; wave w computes rows [w*16, w*16+16). FENCE-FREE protocol: all
// cross-step h traffic via relaxed agent-scope (sc1) atomics -> coherent at
// MALL, no buffer_wbl2/buffer_inv, L2 keeps E2/hist cached. Ordering:
// h stores -> __syncthreads (per-wave vmcnt(0) drain + barrier) -> tid0
// relaxed flag store. VMEM retires in order, so flag visible => h visible.
// Flags: 64 uints packed in 4 lines; every wave polls via one 64-lane load.
__global__ __launch_bounds__(256, 1)
void k_scan(const int* __restrict__ hist, const float* __restrict__ Whh,
            const unsigned short* __restrict__ E2,
            unsigned short* __restrict__ hb0, unsigned short* __restrict__ hb1,
            unsigned int* __restrict__ flags, float* __restrict__ out_h) {
  const int tid = threadIdx.x;
  const int lane = tid & 63;
  const int w = tid >> 6;                 // wave index = batch-row group
  const int bid = blockIdx.x;
  const int n0 = bid * 16;                // col base

  // Preload B-fragments: lane holds W_hh[n0+(lane&15)][kk*32+(lane>>4)*8 + j]
  bf16x8 Breg[32];
  {
    const float* wrow = Whh + (size_t)(n0 + (lane & 15)) * H_ + (lane >> 4) * 8;
#pragma unroll
    for (int kk = 0; kk < 32; kk++) {
      float tmp[8];
      *(float4_t*)(tmp)     = *(const float4_t*)(wrow + kk * 32);
      *(float4_t*)(tmp + 4) = *(const float4_t*)(wrow + kk * 32 + 4);
      Breg[kk] = cvt8(tmp);
    }
  }

  const int rowb = w * 16 + ((lane >> 4) << 2);   // C-row base for this lane
  const int colc = lane & 15;                     // C-col (local)

  for (int t = 0; t < T_; t++) {
    const unsigned short* hc = (t & 1) ? hb1 : hb0;
    unsigned short*       hn = (t & 1) ? hb0 : hb1;

    // xi gather via NORMAL cached loads (read-only data; L2 stays warm now).
    // Issued before the poll so latency hides under the wait.
    float xiv[4];
    {
      int tok[4];
#pragma unroll
      for (int r = 0; r < 4; r++) tok[r] = hist[(size_t)(rowb + r) * T_ + t];
#pragma unroll
      for (int r = 0; r < 4; r++)
        xiv[r] = b2f(E2[(size_t)tok[r] * H_ + n0 + colc]);
    }

    // poll: all 64 producers' flags >= t  (one 64-lane load of 4 lines)
    if (t > 0) {
      const unsigned int e = (unsigned int)t;
      for (;;) {
        unsigned int f = __hip_atomic_load(&flags[lane], __ATOMIC_RELAXED,
                                           __HIP_MEMORY_SCOPE_AGENT);
        if (__all(f >= e)) break;
        __builtin_amdgcn_s_sleep(1);
      }
      asm volatile("" ::: "memory");  // compiler fence: keep h loads below
    }

    // A-fragment loads (sc1, from MALL), software-pipelined in 4-kk groups
    // with a double buffer; all indices compile-time after full unroll.
    const ull* arow = (const ull*)(hc + (size_t)(w * 16 + (lane & 15)) * H_ +
                                   (lane >> 4) * 8);
    f32x4 acc0 = (f32x4)0.0f, acc1 = (f32x4)0.0f;
    ull ab[2][8];
#pragma unroll
    for (int i = 0; i < 4; i++) {         // preload group 0 (kk = 0..3)
      ab[0][2 * i]     = ald(arow + i * 8);
      ab[0][2 * i + 1] = ald(arow + i * 8 + 1);
    }
#pragma unroll
    for (int g = 0; g < 8; g++) {
      const int cur = g & 1, nxt = cur ^ 1;
      if (g < 7) {
#pragma unroll
        for (int i = 0; i < 4; i++) {     // issue group g+1 loads
          const int kk = (g + 1) * 4 + i;
          ab[nxt][2 * i]     = ald(arow + kk * 8);
          ab[nxt][2 * i + 1] = ald(arow + kk * 8 + 1);
        }
      }
#pragma unroll
      for (int i = 0; i < 4; i += 2) {    // MFMA group g (kk = 4g..4g+3)
        const int kk = g * 4 + i;
        bf16x8 a0 = mk8(ab[cur][2 * i],     ab[cur][2 * i + 1]);
        bf16x8 a1 = mk8(ab[cur][2 * i + 2], ab[cur][2 * i + 3]);
        acc0 = __builtin_amdgcn_mfma_f32_16x16x32_bf16(a0, Breg[kk],     acc0, 0, 0, 0);
        acc1 = __builtin_amdgcn_mfma_f32_16x16x32_bf16(a1, Breg[kk + 1], acc1, 0, 0, 0);
      }
    }

#pragma unroll
    for (int reg = 0; reg < 4; reg++) {
      int row = rowb + reg;                       // batch index
      float pre = acc0[reg] + acc1[reg] + xiv[reg];
      float hval = tanhf(pre);
      __hip_atomic_store(hn + (size_t)row * H_ + n0 + colc,
                         (unsigned short)f2b(hval),
                         __ATOMIC_RELAXED, __HIP_MEMORY_SCOPE_AGENT);
      if (t == T_ - 1) out_h[(size_t)row * H_ + n0 + colc] = hval;  // fp32
    }

    // order: drain this wave's stores, sync all 4 waves, then signal.
    asm volatile("s_waitcnt vmcnt(0)" ::: "memory");
    __syncthreads();
    if (tid == 0)
      __hip_atomic_store(&flags[bid], (unsigned int)(t + 1),
                         __ATOMIC_RELAXED, __HIP_MEMORY_SCOPE_AGENT);
  }
}

// ---------------- logits = h_final @ W_cls^T + b ----------------
// grid 500 blocks (64 vocab cols each), 256 threads
__global__ __launch_bounds__(256)
void k_logits(const unsigned short* __restrict__ hb,
              const float* __restrict__ Wcls, const float* __restrict__ bcls,
              float* __restrict__ out) {
  __shared__ unsigned char Bs[64 * 128];
  const int tid = threadIdx.x;
  const int lane = tid & 63;
  const int w = tid >> 6;
  const int n0 = blockIdx.x * 64;
  f32x4 acc[4];
#pragma unroll
  for (int i = 0; i < 4; i++) acc[i] = (f32x4)0.0f;

  for (int kc = 0; kc < H_ / BK; kc++) {
    const int k0 = kc * BK;
    __syncthreads();
#pragma unroll
    for (int it = 0; it < 2; it++) {
      int idx = tid + it * 256;
      int r = idx >> 3;
      int k = (idx & 7) * 8;
      float tmp[8];
      *(float4_t*)(tmp)     = *(const float4_t*)(Wcls + (size_t)(n0 + r) * H_ + k0 + k);
      *(float4_t*)(tmp + 4) = *(const float4_t*)(Wcls + (size_t)(n0 + r) * H_ + k0 + k + 4);
      *(bf16x8*)(Bs + swz128(r, k * 2)) = cvt8(tmp);
    }
    __syncthreads();
#pragma unroll
    for (int kk = 0; kk < 2; kk++) {
      const unsigned short* ap =
          hb + (size_t)(w * 16 + (lane & 15)) * H_ + k0 + kk * 32 + (lane >> 4) * 8;
      bf16x8 a = *(const bf16x8*)ap;
      int kb = kk * 64 + (lane >> 4) * 16;
#pragma unroll
      for (int nt = 0; nt < 4; nt++) {
        bf16x8 b = *(const bf16x8*)(Bs + swz128(nt * 16 + (lane & 15), kb));
        acc[nt] = __builtin_amdgcn_mfma_f32_16x16x32_bf16(a, b, acc[nt], 0, 0, 0);
      }
    }
  }
#pragma unroll
  for (int nt = 0; nt < 4; nt++) {
    int col = n0 + nt * 16 + (lane & 15);
    float bias = bcls[col];
#pragma unroll
    for (int reg = 0; reg < 4; reg++) {
      int row = w * 16 + (lane >> 4) * 4 + reg;
      out[(size_t)row * V_ + col] = acc[nt][reg] + bias;
    }
  }
}

extern "C" void kernel_launch(void* const* d_in, const int* in_sizes, int n_in,
                              void* d_out, int out_size, void* d_ws, size_t ws_size,
                              hipStream_t stream) {
  const int*   hist = (const int*)d_in[0];
  const float* emb  = (const float*)d_in[1];
  const float* Wih  = (const float*)d_in[2];
  const float* Whh  = (const float*)d_in[3];
  const float* Wcls = (const float*)d_in[4];
  const float* bcls = (const float*)d_in[5];
  float* out = (float*)d_out;

  unsigned char* ws = (unsigned char*)d_ws;
  const size_t E2_BYTES = (size_t)V_ * H_ * 2;        // 65,536,000
  const size_t HB_BYTES = (size_t)B_ * H_ * 2;        // 131,072
  unsigned short* E2    = (unsigned short*)ws;
  unsigned short* hb0   = (unsigned short*)(ws + E2_BYTES);
  unsigned short* hb1   = (unsigned short*)(ws + E2_BYTES + HB_BYTES);
  unsigned int*   flags = (unsigned int*)(ws + E2_BYTES + 2 * HB_BYTES);

  k_init<<<256, 256, 0, stream>>>(hb0, flags);
  k_e2<<<dim3(16, 500), 256, 0, stream>>>(emb, Wih, E2);
  k_scan<<<64, 256, 0, stream>>>(hist, Whh, E2, hb0, hb1, flags,
                                 out + (size_t)B_ * V_);
  k_logits<<<500, 256, 0, stream>>>(hb0, Wcls, bcls, out);
}

// Round 5
// 2314.936 us; speedup vs baseline: 3.1158x; 2.2682x over previous
//
#include <hip/hip_runtime.h>
#include <hip/hip_bf16.h>
#include <cstdint>
#include <cstddef>

#define B_ 64
#define T_ 512
#define E_ 512
#define H_ 1024
#define V_ 32000
#define BK 64

typedef __attribute__((ext_vector_type(8))) short bf16x8;
typedef __attribute__((ext_vector_type(4))) float f32x4;
typedef __attribute__((ext_vector_type(4))) float float4_t;
typedef unsigned long long ull;

static __device__ __forceinline__ unsigned short f2b(float f) {
  union { float f; unsigned int u; } v; v.f = f;
  unsigned int u = v.u;
  unsigned int r = (u + 0x7FFFu + ((u >> 16) & 1u)) >> 16;  // RNE
  return (unsigned short)r;
}
static __device__ __forceinline__ float b2f(unsigned short s) {
  union { unsigned int u; float f; } v; v.u = ((unsigned int)s) << 16;
  return v.f;
}
static __device__ __forceinline__ bf16x8 cvt8(const float* p) {
  bf16x8 r;
#pragma unroll
  for (int i = 0; i < 8; i++) r[i] = (short)f2b(p[i]);
  return r;
}
static __device__ __forceinline__ bf16x8 mk8(ull lo, ull hi) {
  union { ull u[2]; bf16x8 v; } c; c.u[0] = lo; c.u[1] = hi; return c.v;
}
// relaxed agent-scope 8B load/stores: coherent at MALL, no cache maintenance
static __device__ __forceinline__ ull ald(const ull* p) {
  return __hip_atomic_load(p, __ATOMIC_RELAXED, __HIP_MEMORY_SCOPE_AGENT);
}
static __device__ __forceinline__ void ast16(unsigned short* p, unsigned short v) {
  __hip_atomic_store(p, v, __ATOMIC_RELAXED, __HIP_MEMORY_SCOPE_AGENT);
}
// LDS swizzle for 128-byte rows (BK=64 bf16): spread 16 rows across banks
static __device__ __forceinline__ int swz128(int row, int byte_off) {
  return row * 128 + (byte_off ^ ((row & 7) << 4));
}

#define NFLAGS 256

// ---------------- init: zero h0 and flag array ----------------
__global__ void k_init(unsigned short* hb0, unsigned int* flags) {
  int i = blockIdx.x * blockDim.x + threadIdx.x;
  if (i < B_ * H_) hb0[i] = 0;  // bf16 zero
  if (i < NFLAGS) flags[i] = 0u;
}

// ---------------- E2 = emb @ W_ih^T  [V,H] bf16 ----------------
// grid (16, 500), 256 threads, 64x64 tile, BK=64
__global__ __launch_bounds__(256)
void k_e2(const float* __restrict__ emb, const float* __restrict__ Wih,
          unsigned short* __restrict__ E2) {
  __shared__ unsigned char As[64 * 128];
  __shared__ unsigned char Bs[64 * 128];
  const int tid = threadIdx.x;
  const int lane = tid & 63;
  const int w = tid >> 6;                 // wave id = M sub-tile
  const int n0 = blockIdx.x * 64;         // over H
  const int m0 = blockIdx.y * 64;         // over V
  f32x4 acc[4];
#pragma unroll
  for (int i = 0; i < 4; i++) acc[i] = (f32x4)0.0f;

  for (int kc = 0; kc < E_ / BK; kc++) {
    const int k0 = kc * BK;
    __syncthreads();
#pragma unroll
    for (int it = 0; it < 2; it++) {
      int idx = tid + it * 256;           // 512 chunks of 8
      int r = idx >> 3;                   // 0..63
      int k = (idx & 7) * 8;              // 0..56
      float tmp[8];
      *(float4_t*)(tmp)     = *(const float4_t*)(emb + (size_t)(m0 + r) * E_ + k0 + k);
      *(float4_t*)(tmp + 4) = *(const float4_t*)(emb + (size_t)(m0 + r) * E_ + k0 + k + 4);
      *(bf16x8*)(As + swz128(r, k * 2)) = cvt8(tmp);
      *(float4_t*)(tmp)     = *(const float4_t*)(Wih + (size_t)(n0 + r) * E_ + k0 + k);
      *(float4_t*)(tmp + 4) = *(const float4_t*)(Wih + (size_t)(n0 + r) * E_ + k0 + k + 4);
      *(bf16x8*)(Bs + swz128(r, k * 2)) = cvt8(tmp);
    }
    __syncthreads();
#pragma unroll
    for (int kk = 0; kk < 2; kk++) {
      int kb = kk * 64 + (lane >> 4) * 16;
      bf16x8 a = *(const bf16x8*)(As + swz128(w * 16 + (lane & 15), kb));
#pragma unroll
      for (int nt = 0; nt < 4; nt++) {
        bf16x8 b = *(const bf16x8*)(Bs + swz128(nt * 16 + (lane & 15), kb));
        acc[nt] = __builtin_amdgcn_mfma_f32_16x16x32_bf16(a, b, acc[nt], 0, 0, 0);
      }
    }
  }
#pragma unroll
  for (int nt = 0; nt < 4; nt++) {
#pragma unroll
    for (int reg = 0; reg < 4; reg++) {
      int row = m0 + w * 16 + (lane >> 4) * 4 + reg;
      int col = n0 + nt * 16 + (lane & 15);
      E2[(size_t)row * H_ + col] = f2b(acc[nt][reg]);
    }
  }
}

// ---------------- persistent scan over T ----------------
// 4 independent groups x 16 blocks. Group g owns batch rows [16g,16g+16);
// block j of the group owns h-cols [64j, 64j+64) with its W_hh slice in
// registers. Per step a block pulls ONLY its group's h slice (32 KB,
// coalesced; wave w fetches K-chunks [8w,8w+8) -> no redundancy), stages in
// LDS (XOR swizzle), and all 4 waves compute C[16 rows x 16 cols].
// Aggregate exchange: 2 MB/step (vs 8 MB for col-partitioning).
// Sync: 16 flags per group packed in one 64B line; fence-free protocol
// (stores -> vmcnt(0) -> barrier -> relaxed flag store), R4-validated.
// XCD mapping: group g = blocks with (bid&7) in {2g,2g+1} -> 2 XCDs/group.
__global__ __launch_bounds__(256, 1)
void k_scan(const int* __restrict__ hist, const float* __restrict__ Whh,
            const unsigned short* __restrict__ E2,
            unsigned short* __restrict__ hb0, unsigned short* __restrict__ hb1,
            unsigned int* __restrict__ flags, float* __restrict__ out_h) {
  const int tid = threadIdx.x;
  const int lane = tid & 63;
  const int w = tid >> 6;                 // wave id
  const int bid = blockIdx.x;
  const int g = (bid & 7) >> 1;           // group (batch rows 16g..16g+16)
  const int j = ((bid >> 3) << 1) + (bid & 1);  // col-slice id in [0,16)
  const int row0 = g * 16;                // global batch-row base
  const int col0 = j * 64;                // global col base of this block
  const int wcol0 = col0 + w * 16;        // this wave's 16 cols

  __shared__ unsigned char hs[16 * 2048]; // h slice [16 rows][1024] swizzled

  const int ar = lane & 15;               // row index within 16
  const int hi = lane >> 4;               // 0..3
  const int swb = (ar & 7) << 4;          // row XOR swizzle

  // B-frags: lane holds W_hh[wcol0+ar][kk*32 + hi*8 + 0..8)
  bf16x8 Breg[32];
  {
    const float* wrow = Whh + (size_t)(wcol0 + ar) * H_ + hi * 8;
#pragma unroll
    for (int kk = 0; kk < 32; kk++) {
      float tmp[8];
      *(float4_t*)(tmp)     = *(const float4_t*)(wrow + kk * 32);
      *(float4_t*)(tmp + 4) = *(const float4_t*)(wrow + kk * 32 + 4);
      Breg[kk] = cvt8(tmp);
    }
  }

  unsigned int* gflags = flags + g * 16;  // one 64B line per group

  for (int t = 0; t < T_; t++) {
    const unsigned short* hc = (t & 1) ? hb1 : hb0;
    unsigned short*       hn = (t & 1) ? hb0 : hb1;

    // xi gather (plain cached loads, read-only data), issued early
    float xiv[4];
    {
      int tok[4];
#pragma unroll
      for (int r = 0; r < 4; r++)
        tok[r] = hist[(size_t)(row0 + hi * 4 + r) * T_ + t];
#pragma unroll
      for (int r = 0; r < 4; r++)
        xiv[r] = b2f(E2[(size_t)tok[r] * H_ + wcol0 + ar]);
    }

    // wait for this group's 16 producers
    if (t > 0) {
      const unsigned int e = (unsigned int)t;
      for (;;) {
        unsigned int f = __hip_atomic_load(&gflags[ar], __ATOMIC_RELAXED,
                                           __HIP_MEMORY_SCOPE_AGENT);
        if (__all(f >= e)) break;
        __builtin_amdgcn_s_sleep(1);
      }
      asm volatile("" ::: "memory");      // keep h loads below the poll
    }

    // pull h slice: wave w fetches K-chunks [8w, 8w+8): lane -> row ar,
    // 16B at byte kk*64 + hi*16. Fully coalesced (16 full lines/instr).
    {
      const ull* hrow = (const ull*)(hc + (size_t)(row0 + ar) * H_);
      ull hv[16];
#pragma unroll
      for (int c = 0; c < 8; c++) {
        const int kk = w * 8 + c;
        hv[2 * c]     = ald(hrow + kk * 8 + hi * 2);
        hv[2 * c + 1] = ald(hrow + kk * 8 + hi * 2 + 1);
      }
#pragma unroll
      for (int c = 0; c < 8; c++) {
        const int kk = w * 8 + c;
        const int b = (kk * 64 + hi * 16) ^ swb;
        *(bf16x8*)(hs + ar * 2048 + b) = mk8(hv[2 * c], hv[2 * c + 1]);
      }
    }
    __syncthreads();

    // C[16x16] = h[16x1024] @ Wslice[16x1024]^T
    f32x4 acc0 = (f32x4)0.0f, acc1 = (f32x4)0.0f;
    {
      const unsigned char* arow_l = hs + ar * 2048;
#pragma unroll
      for (int kk = 0; kk < 32; kk += 2) {
        bf16x8 a0 = *(const bf16x8*)(arow_l + (((kk)     * 64 + hi * 16) ^ swb));
        bf16x8 a1 = *(const bf16x8*)(arow_l + (((kk + 1) * 64 + hi * 16) ^ swb));
        acc0 = __builtin_amdgcn_mfma_f32_16x16x32_bf16(a0, Breg[kk],     acc0, 0, 0, 0);
        acc1 = __builtin_amdgcn_mfma_f32_16x16x32_bf16(a1, Breg[kk + 1], acc1, 0, 0, 0);
      }
    }

#pragma unroll
    for (int reg = 0; reg < 4; reg++) {
      const int lrow = hi * 4 + reg;      // local batch row (C layout)
      float pre = acc0[reg] + acc1[reg] + xiv[reg];
      float hval = tanhf(pre);
      ast16(hn + (size_t)(row0 + lrow) * H_ + wcol0 + ar, f2b(hval));
      if (t == T_ - 1) out_h[(size_t)(row0 + lrow) * H_ + wcol0 + ar] = hval;
    }

    // order: drain stores, sync 4 waves, signal
    asm volatile("s_waitcnt vmcnt(0)" ::: "memory");
    __syncthreads();
    if (tid == 0)
      __hip_atomic_store(&gflags[j], (unsigned int)(t + 1),
                         __ATOMIC_RELAXED, __HIP_MEMORY_SCOPE_AGENT);
  }
}

// ---------------- logits = h_final @ W_cls^T + b ----------------
// grid 500 blocks (64 vocab cols each), 256 threads
__global__ __launch_bounds__(256)
void k_logits(const unsigned short* __restrict__ hb,
              const float* __restrict__ Wcls, const float* __restrict__ bcls,
              float* __restrict__ out) {
  __shared__ unsigned char Bs[64 * 128];
  const int tid = threadIdx.x;
  const int lane = tid & 63;
  const int w = tid >> 6;
  const int n0 = blockIdx.x * 64;
  f32x4 acc[4];
#pragma unroll
  for (int i = 0; i < 4; i++) acc[i] = (f32x4)0.0f;

  for (int kc = 0; kc < H_ / BK; kc++) {
    const int k0 = kc * BK;
    __syncthreads();
#pragma unroll
    for (int it = 0; it < 2; it++) {
      int idx = tid + it * 256;
      int r = idx >> 3;
      int k = (idx & 7) * 8;
      float tmp[8];
      *(float4_t*)(tmp)     = *(const float4_t*)(Wcls + (size_t)(n0 + r) * H_ + k0 + k);
      *(float4_t*)(tmp + 4) = *(const float4_t*)(Wcls + (size_t)(n0 + r) * H_ + k0 + k + 4);
      *(bf16x8*)(Bs + swz128(r, k * 2)) = cvt8(tmp);
    }
    __syncthreads();
#pragma unroll
    for (int kk = 0; kk < 2; kk++) {
      const unsigned short* ap =
          hb + (size_t)(w * 16 + (lane & 15)) * H_ + k0 + kk * 32 + (lane >> 4) * 8;
      bf16x8 a = *(const bf16x8*)ap;
      int kb = kk * 64 + (lane >> 4) * 16;
#pragma unroll
      for (int nt = 0; nt < 4; nt++) {
        bf16x8 b = *(const bf16x8*)(Bs + swz128(nt * 16 + (lane & 15), kb));
        acc[nt] = __builtin_amdgcn_mfma_f32_16x16x32_bf16(a, b, acc[nt], 0, 0, 0);
      }
    }
  }
#pragma unroll
  for (int nt = 0; nt < 4; nt++) {
    int col = n0 + nt * 16 + (lane & 15);
    float bias = bcls[col];
#pragma unroll
    for (int reg = 0; reg < 4; reg++) {
      int row = w * 16 + (lane >> 4) * 4 + reg;
      out[(size_t)row * V_ + col] = acc[nt][reg] + bias;
    }
  }
}

extern "C" void kernel_launch(void* const* d_in, const int* in_sizes, int n_in,
                              void* d_out, int out_size, void* d_ws, size_t ws_size,
                              hipStream_t stream) {
  const int*   hist = (const int*)d_in[0];
  const float* emb  = (const float*)d_in[1];
  const float* Wih  = (const float*)d_in[2];
  const float* Whh  = (const float*)d_in[3];
  const float* Wcls = (const float*)d_in[4];
  const float* bcls = (const float*)d_in[5];
  float* out = (float*)d_out;

  unsigned char* ws = (unsigned char*)d_ws;
  const size_t E2_BYTES = (size_t)V_ * H_ * 2;        // 65,536,000
  const size_t HB_BYTES = (size_t)B_ * H_ * 2;        // 131,072
  unsigned short* E2    = (unsigned short*)ws;
  unsigned short* hb0   = (unsigned short*)(ws + E2_BYTES);
  unsigned short* hb1   = (unsigned short*)(ws + E2_BYTES + HB_BYTES);
  unsigned int*   flags = (unsigned int*)(ws + E2_BYTES + 2 * HB_BYTES);

  k_init<<<256, 256, 0, stream>>>(hb0, flags);
  k_e2<<<dim3(16, 500), 256, 0, stream>>>(emb, Wih, E2);
  k_scan<<<64, 256, 0, stream>>>(hist, Whh, E2, hb0, hb1, flags,
                                 out + (size_t)B_ * V_);
  k_logits<<<500, 256, 0, stream>>>(hb0, Wcls, bcls, out);
}